// Round 1
// baseline (32.989 us; speedup 1.0000x reference)
//
#include <hip/hip_runtime.h>
#include <hip/hip_bf16.h>

// Problem: T=256, B=8, H1=512, U=64, H2=512, V=128
//   pf = einsum('tbh,hv->btv', f, W[:512])   -> rows r = b*256+t      (2048 rows)
//   pg = einsum('buh,hv->buv', g, W[512:])   -> rows r = 2048+b*64+u  ( 512 rows)
//   h[b,t,u,v] = pf[b,t,v] + pg[b,u,v] + bias[v]   (8,256,64,128) f32
// plus f_lens passthrough (8 ints -> float tail of d_out).

typedef float  f32x4  __attribute__((ext_vector_type(4)));
typedef short  bh8    __attribute__((ext_vector_type(8)));

__device__ __forceinline__ unsigned short f2bf(float x) {
    unsigned u = __float_as_uint(x);
    unsigned r = u + 0x7FFFu + ((u >> 16) & 1u);   // round-to-nearest-even
    return (unsigned short)(r >> 16);
}

// ---------------- K0: W (1024x128 f32) -> Wt (128x1024 bf16, transposed) -------------
__global__ __launch_bounds__(256) void wtrans(const float* __restrict__ W,
                                              short* __restrict__ Wt) {
    int gid  = blockIdx.x * 256 + threadIdx.x;   // 64 blocks * 256 thr * 8 = 131072
    int base = gid * 8;
    int h = base >> 7;        // row of W
    int v = base & 127;       // 8 consecutive v
#pragma unroll
    for (int i = 0; i < 8; ++i) {
        Wt[(v + i) * 1024 + h] = (short)f2bf(W[h * 128 + v + i]);
    }
}

// ---------------- K1: fused GEMM, M=2560, N=128, K=512, bf16 MFMA --------------------
// P[r][v] f32.  BM=64 (40 blocks), BN=128, BK=32. 256 threads = 4 waves, wave w owns
// rows [w*16, w*16+16) x 128 cols -> 8 accumulators of 16x16.
__global__ __launch_bounds__(256) void proj_mfma(const float* __restrict__ F,
                                                 const float* __restrict__ G,
                                                 const short* __restrict__ Wt,
                                                 float* __restrict__ P) {
    __shared__ short As[64 * 32];    // 4 KB, row stride 32 shorts (64 B), XOR-swizzled chunks
    __shared__ short Bs[128 * 32];   // 8 KB, same layout (row = n)

    const int tid = threadIdx.x;
    const int blk = blockIdx.x;
    const int rowBase = blk * 64;
    const bool isF = rowBase < 2048;           // block-uniform (2048 % 64 == 0)
    const int koff = isF ? 0 : 512;            // which half of W

    // ---- A staging: thread -> (arow, 8-k chunk ac) ----
    const int arow = tid >> 2;                 // 0..63
    const int ac   = tid & 3;                  // chunk of 8 k
    const int r    = rowBase + arow;
    const float* asrc;
    if (isF) { int b = r >> 8, t = r & 255; asrc = F + ((t << 3) + b) * 512 + ac * 8; }
    else     { asrc = G + (r - 2048) * 512 + ac * 8; }
    const f32x4* ap = reinterpret_cast<const f32x4*>(asrc);
    short* aw = As + arow * 32 + ((ac ^ ((arow >> 1) & 3)) << 3);

    // ---- B staging: thread -> (n = tid>>1, two 8-k chunks) ----
    const int bn  = tid >> 1;                  // 0..127
    const int bc0 = (tid & 1) * 2;
    const short* bsrc = Wt + bn * 1024 + koff + bc0 * 8;
    const bh8* bp = reinterpret_cast<const bh8*>(bsrc);
    short* bw0 = Bs + bn * 32 + (((bc0 + 0) ^ ((bn >> 1) & 3)) << 3);
    short* bw1 = Bs + bn * 32 + (((bc0 + 1) ^ ((bn >> 1) & 3)) << 3);

    // ---- compute-side addressing ----
    const int lane = tid & 63, wid = tid >> 6;
    const int l15  = lane & 15;
    const int cc   = lane >> 4;                     // k-chunk of the fragment
    const int sw   = (l15 >> 1) & 3;                // same swizzle for A and B reads
    const int crow = wid * 16 + l15;
    const short* ard = As + crow * 32 + ((cc ^ sw) << 3);

    f32x4 acc[8] = {};

    // register double-buffer staging
    f32x4 ax0 = ap[0], ax1 = ap[1];
    bh8   bx0 = bp[0], bx1 = bp[1];

    for (int kt = 0; kt < 16; ++kt) {
        // convert A to bf16
        bh8 av;
        av[0] = (short)f2bf(ax0[0]); av[1] = (short)f2bf(ax0[1]);
        av[2] = (short)f2bf(ax0[2]); av[3] = (short)f2bf(ax0[3]);
        av[4] = (short)f2bf(ax1[0]); av[5] = (short)f2bf(ax1[1]);
        av[6] = (short)f2bf(ax1[2]); av[7] = (short)f2bf(ax1[3]);

        __syncthreads();                              // previous compute done
        *reinterpret_cast<bh8*>(aw)  = av;
        *reinterpret_cast<bh8*>(bw0) = bx0;
        *reinterpret_cast<bh8*>(bw1) = bx1;
        __syncthreads();

        if (kt < 15) {                                // prefetch next K-tile
            ax0 = ap[(kt + 1) * 8];     ax1 = ap[(kt + 1) * 8 + 1];
            bx0 = bp[(kt + 1) * 4];     bx1 = bp[(kt + 1) * 4 + 1];
        }

        bh8 a = *reinterpret_cast<const bh8*>(ard);
#pragma unroll
        for (int j = 0; j < 8; ++j) {
            const short* brd = Bs + (j * 16 + l15) * 32 + ((cc ^ sw) << 3);
            bh8 bb = *reinterpret_cast<const bh8*>(brd);
            acc[j] = __builtin_amdgcn_mfma_f32_16x16x32_bf16(a, bb, acc[j], 0, 0, 0);
        }
    }

    // epilogue: D mapping col = lane&15, row = (lane>>4)*4 + reg
    const int r0 = rowBase + wid * 16 + (lane >> 4) * 4;
#pragma unroll
    for (int j = 0; j < 8; ++j) {
#pragma unroll
        for (int q = 0; q < 4; ++q) {
            P[(r0 + q) * 128 + j * 16 + l15] = acc[j][q];
        }
    }
}

// ---------------- K2: broadcast add + stream out + lens tail -------------------------
__global__ __launch_bounds__(256) void bcast(const float* __restrict__ P,
                                             const float* __restrict__ bias,
                                             const int* __restrict__ f_lens,
                                             float* __restrict__ out,
                                             int lens_off) {
    const int r   = blockIdx.x;        // b*256 + t
    const int tid = threadIdx.x;
    const int b   = r >> 8;
    const int vq  = tid & 31;          // float4 index in V
    const int u0  = tid >> 5;          // 0..7

    f32x4 pf = *reinterpret_cast<const f32x4*>(P + r * 128 + vq * 4);
    f32x4 bi = *reinterpret_cast<const f32x4*>(bias + vq * 4);
    pf += bi;

    const float* pg = P + (2048 + b * 64) * 128;
    float* ob = out + (size_t)r * 8192;

#pragma unroll
    for (int i = 0; i < 8; ++i) {
        int u = u0 * 8 + i;
        f32x4 v = *reinterpret_cast<const f32x4*>(pg + u * 128 + vq * 4);
        v += pf;
        *reinterpret_cast<f32x4*>(ob + u * 128 + vq * 4) = v;
    }

    if (r == 0 && tid < 8) out[lens_off + tid] = (float)f_lens[tid];
}

extern "C" void kernel_launch(void* const* d_in, const int* in_sizes, int n_in,
                              void* d_out, int out_size, void* d_ws, size_t ws_size,
                              hipStream_t stream) {
    const float* f      = (const float*)d_in[0];
    const int*   f_lens = (const int*)  d_in[1];
    const float* g      = (const float*)d_in[2];
    // d_in[3] = g_lens (unused by reference output)
    const float* W      = (const float*)d_in[4];
    const float* bias   = (const float*)d_in[5];
    float* out = (float*)d_out;

    short* Wt = (short*)d_ws;                                  // 128*1024*2 = 256 KB
    float* P  = (float*)((char*)d_ws + 262144);                // 2560*128*4 = 1.25 MB

    wtrans   <<<dim3(64),   dim3(256), 0, stream>>>(W, Wt);
    proj_mfma<<<dim3(40),   dim3(256), 0, stream>>>(f, g, Wt, P);
    bcast    <<<dim3(2048), dim3(256), 0, stream>>>(P, bias, f_lens, out, out_size - 8);
}

// Round 2
// 28.909 us; speedup vs baseline: 1.1412x; 1.1412x over previous
//
#include <hip/hip_runtime.h>
#include <hip/hip_bf16.h>

// Problem: T=256, B=8, H1=512, U=64, H2=512, V=128
//   pf = einsum('tbh,hv->btv', f, W[:512])   -> rows r = b*256+t      (2048 rows)
//   pg = einsum('buh,hv->buv', g, W[512:])   -> rows r = 2048+b*64+u  ( 512 rows)
//   h[b,t,u,v] = pf[b,t,v] + pg[b,u,v] + bias[v]   (8,256,64,128) f32
// plus f_lens passthrough (8 ints -> float tail of d_out).

typedef float  f32x4  __attribute__((ext_vector_type(4)));
typedef short  bh8    __attribute__((ext_vector_type(8)));

__device__ __forceinline__ unsigned short f2bf(float x) {
    unsigned u = __float_as_uint(x);
    unsigned r = u + 0x7FFFu + ((u >> 16) & 1u);   // round-to-nearest-even
    return (unsigned short)(r >> 16);
}

// ---------------- K0: W (1024x128 f32) -> Wt (128x1024 bf16, transposed) -------------
// Coalesced reads (lane = v), each thread emits 16 contiguous bf16 (2x16B stores).
__global__ __launch_bounds__(256) void wtrans2(const float* __restrict__ W,
                                               short* __restrict__ Wt) {
    int gid = blockIdx.x * 256 + threadIdx.x;    // 32 blocks -> 8192 threads
    int v   = gid & 127;
    int h0  = (gid >> 7) * 16;                   // 64 h-chunks
    short tmp[16];
#pragma unroll
    for (int i = 0; i < 16; ++i)
        tmp[i] = (short)f2bf(W[(h0 + i) * 128 + v]);
    bh8* dst = reinterpret_cast<bh8*>(Wt + v * 1024 + h0);
    dst[0] = *reinterpret_cast<bh8*>(&tmp[0]);
    dst[1] = *reinterpret_cast<bh8*>(&tmp[8]);
}

// ---------------- K1: GEMM M=2560,N=128,K=512; 160 blocks, wave-split-K --------------
// Block = 16-row M-tile. 4 waves, wave w covers k in [w*128, w*128+128) (4 MFMA steps).
// A fragments straight from global f/g (f32 -> bf16 in regs), B straight from Wt (L2).
// Cross-wave reduce through LDS, then coalesced P write.
__global__ __launch_bounds__(256) void proj2(const float* __restrict__ F,
                                             const float* __restrict__ G,
                                             const short* __restrict__ Wt,
                                             float* __restrict__ P) {
    __shared__ float red[4][16][128];            // 32 KB

    const int tid  = threadIdx.x;
    const int w    = tid >> 6;                   // wave id = K quarter
    const int lane = tid & 63;
    const int l15  = lane & 15;
    const int cc   = lane >> 4;                  // k-chunk within fragment
    const int rowBase = blockIdx.x * 16;
    const bool isF = rowBase < 2048;
    const int koff = isF ? 0 : 512;              // W half (in Wt k index)

    // A source row pointer (per lane): row r = rowBase + l15
    const int r = rowBase + l15;
    const float* arow;
    if (isF) { int b = r >> 8, t = r & 255; arow = F + ((t << 3) + b) * 512; }
    else     { arow = G + (r - 2048) * 512; }

    f32x4 acc[8] = {};

#pragma unroll
    for (int kk = 0; kk < 4; ++kk) {
        const int k0 = w * 128 + kk * 32 + cc * 8;   // this lane's 8-k chunk
        // A fragment: 8 consecutive f32 -> bf16
        f32x4 a0 = *reinterpret_cast<const f32x4*>(arow + k0);
        f32x4 a1 = *reinterpret_cast<const f32x4*>(arow + k0 + 4);
        bh8 av;
        av[0] = (short)f2bf(a0[0]); av[1] = (short)f2bf(a0[1]);
        av[2] = (short)f2bf(a0[2]); av[3] = (short)f2bf(a0[3]);
        av[4] = (short)f2bf(a1[0]); av[5] = (short)f2bf(a1[1]);
        av[6] = (short)f2bf(a1[2]); av[7] = (short)f2bf(a1[3]);
        // B fragments: Wt[v][k] rows, 16B contiguous per lane
#pragma unroll
        for (int j = 0; j < 8; ++j) {
            const short* bsrc = Wt + (j * 16 + l15) * 1024 + koff + k0;
            bh8 bv = *reinterpret_cast<const bh8*>(bsrc);
            acc[j] = __builtin_amdgcn_mfma_f32_16x16x32_bf16(av, bv, acc[j], 0, 0, 0);
        }
    }

    // stash partials: D elem (row = cc*4+q, col = j*16+l15)
#pragma unroll
    for (int j = 0; j < 8; ++j)
#pragma unroll
        for (int q = 0; q < 4; ++q)
            red[w][cc * 4 + q][j * 16 + l15] = acc[j][q];
    __syncthreads();

    // reduce 4 waves and write P: thread -> (row = tid>>4, 8 cols at (tid&15)*8)
    const int row = tid >> 4, colq = tid & 15;
    f32x4 s0 = {}, s1 = {};
#pragma unroll
    for (int ww = 0; ww < 4; ++ww) {
        s0 += *reinterpret_cast<const f32x4*>(&red[ww][row][colq * 8]);
        s1 += *reinterpret_cast<const f32x4*>(&red[ww][row][colq * 8 + 4]);
    }
    float* pdst = P + (rowBase + row) * 128 + colq * 8;
    *reinterpret_cast<f32x4*>(pdst)     = s0;
    *reinterpret_cast<f32x4*>(pdst + 4) = s1;
}

// ---------------- K2: broadcast add + stream out + lens tail -------------------------
__global__ __launch_bounds__(256) void bcast(const float* __restrict__ P,
                                             const float* __restrict__ bias,
                                             const int* __restrict__ f_lens,
                                             float* __restrict__ out,
                                             int lens_off) {
    const int r   = blockIdx.x;        // b*256 + t
    const int tid = threadIdx.x;
    const int b   = r >> 8;
    const int vq  = tid & 31;          // float4 index in V
    const int u0  = tid >> 5;          // 0..7

    f32x4 pf = *reinterpret_cast<const f32x4*>(P + r * 128 + vq * 4);
    f32x4 bi = *reinterpret_cast<const f32x4*>(bias + vq * 4);
    pf += bi;

    const float* pg = P + (2048 + b * 64) * 128;
    float* ob = out + (size_t)r * 8192;

#pragma unroll
    for (int i = 0; i < 8; ++i) {
        int u = u0 * 8 + i;
        f32x4 v = *reinterpret_cast<const f32x4*>(pg + u * 128 + vq * 4);
        v += pf;
        *reinterpret_cast<f32x4*>(ob + u * 128 + vq * 4) = v;
    }

    if (r == 0 && tid < 8) out[lens_off + tid] = (float)f_lens[tid];
}

extern "C" void kernel_launch(void* const* d_in, const int* in_sizes, int n_in,
                              void* d_out, int out_size, void* d_ws, size_t ws_size,
                              hipStream_t stream) {
    const float* f      = (const float*)d_in[0];
    const int*   f_lens = (const int*)  d_in[1];
    const float* g      = (const float*)d_in[2];
    // d_in[3] = g_lens (unused by reference output)
    const float* W      = (const float*)d_in[4];
    const float* bias   = (const float*)d_in[5];
    float* out = (float*)d_out;

    short* Wt = (short*)d_ws;                                  // 128*1024*2 = 256 KB
    float* P  = (float*)((char*)d_ws + 262144);                // 2560*128*4 = 1.25 MB

    wtrans2<<<dim3(32),   dim3(256), 0, stream>>>(W, Wt);
    proj2  <<<dim3(160),  dim3(256), 0, stream>>>(f, g, Wt, P);
    bcast  <<<dim3(2048), dim3(256), 0, stream>>>(P, bias, f_lens, out, out_size - 8);
}

// Round 3
// 28.156 us; speedup vs baseline: 1.1716x; 1.0267x over previous
//
#include <hip/hip_runtime.h>
#include <hip/hip_bf16.h>

// T=256, B=8, H1=512, U=64, H2=512, V=128
//   pf[b,t,v] = f[t,b,:]·W[:512,v]      (2048 x 128)
//   pg[b,u,v] = g[b,u,:]·W[512:,v]      ( 512 x 128)
//   out[b,t,u,v] = pf + pg + bias       (8,256,64,128) f32, + f_lens tail (8)

typedef float  f32x4 __attribute__((ext_vector_type(4)));
typedef short  bh8   __attribute__((ext_vector_type(8)));

__device__ __forceinline__ unsigned short f2bf(float x) {
    unsigned u = __float_as_uint(x);
    return (unsigned short)((u + 0x7FFFu + ((u >> 16) & 1u)) >> 16);
}

// ---------------- K1: blocks 0-31 W->Wt transpose; blocks 32-63 pg GEMM -------------
__global__ __launch_bounds__(256) void prep(const float* __restrict__ W,
                                            const float* __restrict__ G,
                                            short* __restrict__ Wt,
                                            float* __restrict__ Pg) {
    __shared__ float red[4][16][128];            // 32 KB (pg role only)
    const int tid = threadIdx.x;

    if (blockIdx.x < 32) {
        // W (1024x128 f32) -> Wt (128x1024 bf16). Coalesced reads (lane = v).
        int gid = blockIdx.x * 256 + tid;
        int v = gid & 127, h0 = (gid >> 7) * 16;
        short tmp[16];
#pragma unroll
        for (int i = 0; i < 16; ++i) tmp[i] = (short)f2bf(W[(h0 + i) * 128 + v]);
        bh8* dst = reinterpret_cast<bh8*>(Wt + v * 1024 + h0);
        dst[0] = *reinterpret_cast<bh8*>(&tmp[0]);
        dst[1] = *reinterpret_cast<bh8*>(&tmp[8]);
        return;
    }

    // pg: rows = b*64+u in [0,512), 16-row tile per block, wave-split-K (4x128).
    const int rowBase = (blockIdx.x - 32) * 16;
    const int w = tid >> 6, lane = tid & 63, l15 = lane & 15, cc = lane >> 4;
    const float* arow = G + (rowBase + l15) * 512;

    f32x4 acc[8] = {};
#pragma unroll
    for (int kk = 0; kk < 4; ++kk) {
        const int k0 = w * 128 + kk * 32 + cc * 8;
        f32x4 a0 = *reinterpret_cast<const f32x4*>(arow + k0);
        f32x4 a1 = *reinterpret_cast<const f32x4*>(arow + k0 + 4);
        bh8 av;
        av[0] = (short)f2bf(a0[0]); av[1] = (short)f2bf(a0[1]);
        av[2] = (short)f2bf(a0[2]); av[3] = (short)f2bf(a0[3]);
        av[4] = (short)f2bf(a1[0]); av[5] = (short)f2bf(a1[1]);
        av[6] = (short)f2bf(a1[2]); av[7] = (short)f2bf(a1[3]);
#pragma unroll
        for (int j = 0; j < 8; ++j) {
            const float* wsrc = W + (512 + k0) * 128 + (j * 16 + l15);
            bh8 bv;
#pragma unroll
            for (int i = 0; i < 8; ++i) bv[i] = (short)f2bf(wsrc[i * 128]);
            acc[j] = __builtin_amdgcn_mfma_f32_16x16x32_bf16(av, bv, acc[j], 0, 0, 0);
        }
    }
#pragma unroll
    for (int j = 0; j < 8; ++j)
#pragma unroll
        for (int q = 0; q < 4; ++q)
            red[w][cc * 4 + q][j * 16 + l15] = acc[j][q];
    __syncthreads();

    const int row = tid >> 4, colq = tid & 15;
    f32x4 s0 = {}, s1 = {};
#pragma unroll
    for (int ww = 0; ww < 4; ++ww) {
        s0 += *reinterpret_cast<const f32x4*>(&red[ww][row][colq * 8]);
        s1 += *reinterpret_cast<const f32x4*>(&red[ww][row][colq * 8 + 4]);
    }
    float* pdst = Pg + (rowBase + row) * 128 + colq * 8;
    *reinterpret_cast<f32x4*>(pdst)     = s0;
    *reinterpret_cast<f32x4*>(pdst + 4) = s1;
}

// ---------------- K2: per-(b,8t) block: pf MFMA + fused broadcast write -------------
__global__ __launch_bounds__(256) void fuse(const float* __restrict__ F,
                                            const short* __restrict__ Wt,
                                            const float* __restrict__ Pg,
                                            const float* __restrict__ bias,
                                            const int* __restrict__ f_lens,
                                            float* __restrict__ out, int lens_off) {
    __shared__ float pfred[4][8][128];           // 16 KB

    const int tid = threadIdx.x;
    const int b = blockIdx.x >> 5, t0 = (blockIdx.x & 31) * 8;
    const int w = tid >> 6, lane = tid & 63, l15 = lane & 15, cc = lane >> 4;

    // pf for rows t0..t0+7 (duplicated to 16 M-rows), wave-split-K (4x128)
    const int t = t0 + (l15 & 7);
    const float* arow = F + (t * 8 + b) * 512;   // f is [T][B][H1]

    f32x4 acc[8] = {};
#pragma unroll
    for (int kk = 0; kk < 4; ++kk) {
        const int k0 = w * 128 + kk * 32 + cc * 8;
        f32x4 a0 = *reinterpret_cast<const f32x4*>(arow + k0);
        f32x4 a1 = *reinterpret_cast<const f32x4*>(arow + k0 + 4);
        bh8 av;
        av[0] = (short)f2bf(a0[0]); av[1] = (short)f2bf(a0[1]);
        av[2] = (short)f2bf(a0[2]); av[3] = (short)f2bf(a0[3]);
        av[4] = (short)f2bf(a1[0]); av[5] = (short)f2bf(a1[1]);
        av[6] = (short)f2bf(a1[2]); av[7] = (short)f2bf(a1[3]);
#pragma unroll
        for (int j = 0; j < 8; ++j) {
            bh8 bv = *reinterpret_cast<const bh8*>(Wt + (j * 16 + l15) * 1024 + k0);
            acc[j] = __builtin_amdgcn_mfma_f32_16x16x32_bf16(av, bv, acc[j], 0, 0, 0);
        }
    }
    // D row m = cc*4+q -> t-row m&7; keep m<8 (cc<2), m>=8 are duplicates
    if (cc < 2) {
#pragma unroll
        for (int j = 0; j < 8; ++j)
#pragma unroll
            for (int q = 0; q < 4; ++q)
                pfred[w][cc * 4 + q][j * 16 + l15] = acc[j][q];
    }
    __syncthreads();

    // epilogue: thread -> (vq = 16B col, ug = u low-3), rows u = ui*8+ug
    const int vq = tid & 31, ug = tid >> 5;
    const f32x4 bi = *reinterpret_cast<const f32x4*>(bias + vq * 4);

    f32x4 pfv[8], pgv[8];
#pragma unroll
    for (int t2 = 0; t2 < 8; ++t2) {
        f32x4 s = *reinterpret_cast<const f32x4*>(&pfred[0][t2][vq * 4]);
        s += *reinterpret_cast<const f32x4*>(&pfred[1][t2][vq * 4]);
        s += *reinterpret_cast<const f32x4*>(&pfred[2][t2][vq * 4]);
        s += *reinterpret_cast<const f32x4*>(&pfred[3][t2][vq * 4]);
        pfv[t2] = s + bi;
    }
#pragma unroll
    for (int ui = 0; ui < 8; ++ui)
        pgv[ui] = *reinterpret_cast<const f32x4*>(Pg + (b * 64 + ui * 8 + ug) * 128 + vq * 4);

    float* ob = out + (size_t)(b * 256 + t0) * 8192;
#pragma unroll
    for (int t2 = 0; t2 < 8; ++t2)
#pragma unroll
        for (int ui = 0; ui < 8; ++ui)
            *reinterpret_cast<f32x4*>(ob + (t2 * 64 + ui * 8 + ug) * 128 + vq * 4)
                = pfv[t2] + pgv[ui];

    if (blockIdx.x == 0 && tid < 8) out[lens_off + tid] = (float)f_lens[tid];
}

extern "C" void kernel_launch(void* const* d_in, const int* in_sizes, int n_in,
                              void* d_out, int out_size, void* d_ws, size_t ws_size,
                              hipStream_t stream) {
    const float* f      = (const float*)d_in[0];
    const int*   f_lens = (const int*)  d_in[1];
    const float* g      = (const float*)d_in[2];
    // d_in[3] = g_lens (unused by reference output)
    const float* W      = (const float*)d_in[4];
    const float* bias   = (const float*)d_in[5];
    float* out = (float*)d_out;

    float* Pg = (float*)d_ws;                                  // 512*128*4 = 256 KB
    short* Wt = (short*)((char*)d_ws + 262144);                // 128*1024*2 = 256 KB

    prep<<<dim3(64),  dim3(256), 0, stream>>>(W, g, Wt, Pg);
    fuse<<<dim3(256), dim3(256), 0, stream>>>(f, Wt, Pg, bias, f_lens, out, out_size - 8);
}